// Round 1
// baseline (92.711 us; speedup 1.0000x reference)
//
#include <hip/hip_runtime.h>
#include <hip/hip_bf16.h>
#include <cstdint>

// Problem constants (reference: BATCH=4096, N_VIEWS=2, T=0.07, D=128 -> N=8192)
#define NROWS 8192
#define FDIM  128
#define HALF_N 4096

typedef short bf16x8 __attribute__((ext_vector_type(8)));   // 8 bf16 = 4 VGPRs
typedef float f32x4  __attribute__((ext_vector_type(4)));

// k1 = log2(e)/T so exp((s-1)/T) = exp2(k1*s - k1)
#define K1 (1.4426950408889634f / 0.07f)

#if __has_builtin(__builtin_amdgcn_exp2f)
#define EXP2(x) __builtin_amdgcn_exp2f(x)       // raw v_exp_f32
#else
#define EXP2(x) exp2f(x)
#endif

// Upper-triangle block count at (128-row x 256-col) granularity:
// per col-group J (0..31), rb = 0..2J+1 kept -> sum(2J+2) = 32*33 = 1056.
#define NBLK_TRI 1056

// Fragment-packed layout of the normalized bf16 matrix:
//   frag (rb, ks) at flat bf16x8 index (rb*4+ks)*64 + lane,
//   lane = quad*16 + (r&15) holds row r = rb*16+(lane&15), k = ks*32+quad*8..+8.
// One coalesced global_load_dwordx4 per fragment. 2 MB total.

// ---------------------------------------------------------------------------
// Kernel 1: L2-normalize rows (fp32, matching ref), write fragment-packed
// bf16. Also zero-inits esum_g.
// ---------------------------------------------------------------------------
__global__ void __launch_bounds__(256) normalize_kernel(const float* __restrict__ f,
                                                        short* __restrict__ packed,
                                                        float* __restrict__ esum_g) {
    const int row  = blockIdx.x * 4 + (threadIdx.x >> 6);
    const int lane = threadIdx.x & 63;           // element k = 2*lane, 2*lane+1
    const float2 v = ((const float2*)(f + (size_t)row * FDIM))[lane];
    float ss = v.x * v.x + v.y * v.y;
    #pragma unroll
    for (int m = 1; m < 64; m <<= 1) ss += __shfl_xor(ss, m);
    const float scale = 1.0f / fmaxf(sqrtf(ss), 1e-12f);

    const int off = ((((row >> 4) * 4 + (lane >> 4)) * 64)
                     + ((lane >> 2) & 3) * 16 + (row & 15)) * 8 + 2 * (lane & 3);
    __hip_bfloat16 b0 = __float2bfloat16(v.x * scale);
    __hip_bfloat16 b1 = __float2bfloat16(v.y * scale);
    unsigned u = (unsigned)*(unsigned short*)&b0
               | ((unsigned)*(unsigned short*)&b1 << 16);
    *(unsigned*)(packed + off) = u;              // 4B-aligned (off is even)

    if (threadIdx.x < 4) esum_g[blockIdx.x * 4 + threadIdx.x] = 0.0f;
}

__device__ __forceinline__ float2 bf2_to_f2(unsigned u) {
    return make_float2(__uint_as_float(u << 16),
                       __uint_as_float(u & 0xffff0000u));
}

// ---------------------------------------------------------------------------
// Kernel 2: SYMMETRIC sim+exp+rowsum. sim = F F^T is symmetric, so only the
// upper triangle of (128-row x 256-col) tiles is computed: block t -> (J, rb)
// with rb <= 2J+1 (1056 blocks).
//   - rb in {2J, 2J+1}: "diagonal" blocks. Their rows lie inside the col
//     range, so the two of them cover the 256x256 diagonal super-tile fully;
//     they contribute ROW sums only (incl. the i==i term, subtracted via
//     diag_g in the final kernel) — identical to the full-matrix kernel.
//   - rb < 2J: strictly-upper blocks. Each e = exp((s_rc-1)/T) feeds BOTH
//     esum[r] (row partials in registers, committed per wave) and esum[c]
//     (per-lane sum of its 8 e's -> shfl_xor across the 4 quads -> ds_add
//     into a 256-float LDS array -> one coalesced global-atomic commit).
// This halves MFMA, exp and B-fragment load work vs the full-matrix version.
// 256-col groups (not 512) keep the grid at 1088 blocks (~4.25 blocks/CU) so
// __launch_bounds__(256,4) still gives 4 waves/SIMD of latency hiding.
// Per wave: 32 rows x 256 cols; A parked in 32 VGPR; per cb (16 cols):
// 4 B-frag loads + 8 MFMA + 8 exp2 per lane; unroll-8 lets the compiler
// hoist loads across iterations.
// Blocks 1056..1087: pos_i = <f_i, f_(i^4096)>, diag_i = exp((<f_i,f_i>-1)/T).
// ---------------------------------------------------------------------------
__global__ void __launch_bounds__(256, 4) sim_kernel(const short* __restrict__ pk,
                                                     float* __restrict__ esum_g,
                                                     float* __restrict__ pos_g,
                                                     float* __restrict__ diag_g) {
    if (blockIdx.x >= NBLK_TRI) {
        // ---- pos/diag path: one thread per row ----
        const int i  = (blockIdx.x - NBLK_TRI) * 256 + threadIdx.x;
        const int ip = i ^ HALF_N;
        const uint4* P = (const uint4*)pk;
        float dot = 0.f, self = 0.f;
        #pragma unroll
        for (int cc = 0; cc < 16; cc++) {        // cc = ks*4 + quad
            const uint4 a = P[((i  >> 4) * 4 + (cc >> 2)) * 64 + (cc & 3) * 16 + (i  & 15)];
            const uint4 b = P[((ip >> 4) * 4 + (cc >> 2)) * 64 + (cc & 3) * 16 + (ip & 15)];
            const unsigned au[4] = {a.x, a.y, a.z, a.w};
            const unsigned bu[4] = {b.x, b.y, b.z, b.w};
            #pragma unroll
            for (int q = 0; q < 4; q++) {
                const float2 av = bf2_to_f2(au[q]);
                const float2 bv = bf2_to_f2(bu[q]);
                dot  = __builtin_fmaf(av.x, bv.x, __builtin_fmaf(av.y, bv.y, dot));
                self = __builtin_fmaf(av.x, av.x, __builtin_fmaf(av.y, av.y, self));
            }
        }
        pos_g[i]  = dot;
        diag_g[i] = EXP2(__builtin_fmaf(self, K1, -K1));
        return;
    }

    // ---- map block id -> (J, rb), rb <= 2J+1; prefix(J) = J*(J+1) ----
    const int t = blockIdx.x;
    int J = (int)((sqrtf(4.0f * (float)t + 1.0f) - 1.0f) * 0.5f);
    while ((J + 1) * (J + 2) <= t) J++;          // fixup float sqrt (scalar)
    while (J * (J + 1) > t) J--;
    const int rb = t - J * (J + 1);              // row block of 128 rows
    const bool upper = rb < 2 * J;               // strictly above the diagonal

    const int tid   = threadIdx.x;
    const int w     = tid >> 6;
    const int lane  = tid & 63;
    const int quad  = lane >> 4;
    const int l16   = lane & 15;
    const int strip = rb * 4 + w;                // 0..255: rows strip*32..+32
    const bf16x8* P = (const bf16x8*)pk;

    __shared__ float colsum[256];
    colsum[tid] = 0.0f;

    // A fragments for this wave's 32 rows, parked: a_reg[ks][fr] (32 VGPR)
    bf16x8 a_reg[4][2];
    #pragma unroll
    for (int fr = 0; fr < 2; fr++)
        #pragma unroll
        for (int ks = 0; ks < 4; ks++)
            a_reg[ks][fr] = P[(((strip * 2 + fr) * 4) + ks) * 64 + lane];

    float ep[2][4];                              // [fr][r] row partials
    #pragma unroll
    for (int a = 0; a < 2; a++)
        #pragma unroll
        for (int b = 0; b < 4; b++) ep[a][b] = 0.0f;

    __syncthreads();                             // colsum init visible to all waves

    const int cb0 = J * 16;                      // 16 col-blocks of 16 cols

    #pragma unroll 8
    for (int cb = 0; cb < 16; cb++) {
        bf16x8 b[4];
        #pragma unroll
        for (int ks = 0; ks < 4; ks++)
            b[ks] = P[((cb0 + cb) * 4 + ks) * 64 + lane];

        f32x4 acc[2];
        #pragma unroll
        for (int fr = 0; fr < 2; fr++) acc[fr] = (f32x4){0.f, 0.f, 0.f, 0.f};
        #pragma unroll
        for (int ks = 0; ks < 4; ks++)
            #pragma unroll
            for (int fr = 0; fr < 2; fr++)
                acc[fr] = __builtin_amdgcn_mfma_f32_16x16x32_bf16(
                              a_reg[ks][fr], b[ks], acc[fr], 0, 0, 0);

        float cs = 0.0f;                         // this lane's col partial (8 rows)
        #pragma unroll
        for (int fr = 0; fr < 2; fr++)
            #pragma unroll
            for (int r = 0; r < 4; r++) {
                const float e = EXP2(__builtin_fmaf(acc[fr][r], K1, -K1));
                ep[fr][r] += e;
                cs += e;
            }

        if (upper) {                             // wave-uniform branch
            cs += __shfl_xor(cs, 16);            // sum the 4 quads -> 32 rows
            cs += __shfl_xor(cs, 32);
            if (quad == 0)
                atomicAdd(&colsum[cb * 16 + l16], cs);   // ds_add_f32, races ok
        }
    }

    // reduce row partials across the 16 column-lanes, commit once per wave
    #pragma unroll
    for (int fr = 0; fr < 2; fr++)
        #pragma unroll
        for (int r = 0; r < 4; r++) {
            float v = ep[fr][r];
            #pragma unroll
            for (int m = 1; m < 16; m <<= 1) v += __shfl_xor(v, m);
            if (l16 == 0)
                atomicAdd(&esum_g[strip * 32 + fr * 16 + quad * 4 + r], v);
        }

    // commit column sums (transpose contribution), one coalesced atomic/thread
    __syncthreads();
    if (upper) atomicAdd(&esum_g[J * 256 + tid], colsum[tid]);
}

// ---------------------------------------------------------------------------
// Kernel 3: loss_i = ln(esum_i - diag_i) + 1/T - pos_i/T ; out = mean(loss).
// ---------------------------------------------------------------------------
__global__ void __launch_bounds__(256) final_kernel(const float* __restrict__ esum_g,
                                                    const float* __restrict__ pos_g,
                                                    const float* __restrict__ diag_g,
                                                    float* __restrict__ out) {
    const int tid = threadIdx.x;
    const float invT = 1.0f / 0.07f;
    float acc = 0.0f;
    for (int i = tid; i < NROWS; i += 256)
        acc += logf(esum_g[i] - diag_g[i]) + invT - pos_g[i] * invT;
    #pragma unroll
    for (int m = 1; m < 64; m <<= 1) acc += __shfl_xor(acc, m);
    __shared__ float ws[4];
    if ((tid & 63) == 0) ws[tid >> 6] = acc;
    __syncthreads();
    if (tid == 0) out[0] = (ws[0] + ws[1] + ws[2] + ws[3]) * (1.0f / (float)NROWS);
}

// ---------------------------------------------------------------------------
extern "C" void kernel_launch(void* const* d_in, const int* in_sizes, int n_in,
                              void* d_out, int out_size, void* d_ws, size_t ws_size,
                              hipStream_t stream) {
    const float* features = (const float*)d_in[0];
    float* out = (float*)d_out;

    char* ws = (char*)d_ws;
    short* packed = (short*)ws;                                          // 2 MB
    float* esum_g = (float*)(ws + 2097152);                              // 32 KB
    float* pos_g  = (float*)(ws + 2097152 + 32768);                      // 32 KB
    float* diag_g = (float*)(ws + 2097152 + 65536);                      // 32 KB

    normalize_kernel<<<NROWS / 4, 256, 0, stream>>>(features, packed, esum_g);

    sim_kernel<<<NBLK_TRI + NROWS / 256, 256, 0, stream>>>(packed, esum_g, pos_g, diag_g);

    final_kernel<<<1, 256, 0, stream>>>(esum_g, pos_g, diag_g, out);
}